// Round 5
// baseline (73014.642 us; speedup 1.0000x reference)
//
#include <hip/hip_runtime.h>

#define Hh 512
#define Bb 256
#define Tt 512
#define NPR 128
#define BH (Bb*Hh)
#define WN (4*Hh*Hh)
#define LDSB (131072 + 256)

typedef __attribute__((ext_vector_type(8))) short bf8;
typedef __attribute__((ext_vector_type(4))) float f4;

#define MF(A,B,C) C = __builtin_amdgcn_mfma_f32_16x16x32_bf16(A,B,C,0,0,0)

__device__ __forceinline__ unsigned short f2bf(float x) {
  unsigned u = __float_as_uint(x);
  return (unsigned short)((u + 0x7FFFu + ((u >> 16) & 1u)) >> 16);
}
__device__ __forceinline__ float bf2f(unsigned short h) {
  return __uint_as_float((unsigned)h << 16);
}

struct KP {
  const float *x, *eb0, *eb1, *db0, *db1, *eWih0, *dWih0, *linW, *linb;
  const unsigned short *eWhh0h,*eWhh0l,*eWih1h,*eWih1l,*eWhh1h,*eWhh1l;
  const unsigned short *dWhh0h,*dWhh0l,*dWih1h,*dWih1l,*dWhh1h,*dWhh1l;
  unsigned short *h0h0,*h0h1,*h0l0,*h0l1,*h1h0,*h1h1,*h1l0,*h1l1;
  float *c0,*c1,*pred,*out;
  unsigned *bar;
};

// ---- hierarchical device-scope grid barrier (16 groups x 16 blocks) ----
__device__ void gsync(unsigned* bar) {
  __syncthreads();
  __threadfence();            // release: write back dirty lines (all waves)
  __syncthreads();            // all waves' writebacks complete before announce
  if (threadIdx.x == 0) {
    const int grp = blockIdx.x >> 4;
    const unsigned g = __hip_atomic_load(bar + 272, __ATOMIC_RELAXED, __HIP_MEMORY_SCOPE_AGENT);
    const unsigned a = __hip_atomic_fetch_add(bar + grp*16, 1u, __ATOMIC_ACQ_REL, __HIP_MEMORY_SCOPE_AGENT);
    if (a == 15u) {
      __hip_atomic_store(bar + grp*16, 0u, __ATOMIC_RELAXED, __HIP_MEMORY_SCOPE_AGENT);
      const unsigned r = __hip_atomic_fetch_add(bar + 256, 1u, __ATOMIC_ACQ_REL, __HIP_MEMORY_SCOPE_AGENT);
      if (r == 15u) {
        __hip_atomic_store(bar + 256, 0u, __ATOMIC_RELAXED, __HIP_MEMORY_SCOPE_AGENT);
        __hip_atomic_store(bar + 272, g + 1u, __ATOMIC_RELEASE, __HIP_MEMORY_SCOPE_AGENT);
      }
    }
    while (__hip_atomic_load(bar + 272, __ATOMIC_ACQUIRE, __HIP_MEMORY_SCOPE_AGENT) == g)
      __builtin_amdgcn_s_sleep(1);
  }
  __syncthreads();
  __threadfence();            // acquire: invalidate stale L1/L2 before reads
}

// ---- one-time weight staging into LDS (XOR-swizzled 16B slots) ----
// role A: 64 rows (g*16+jj), hi slab @0 (64KB), lo slab @65536
__device__ void stageA_w(const unsigned short* Wh, const unsigned short* Wl, int j0, char* L) {
  const int t = threadIdx.x;
  const int r = t >> 2, q = t & 3;
  const int n = (r >> 4)*Hh + j0 + (r & 15);
  const unsigned short* gh = Wh + (size_t)n*Hh;
  const unsigned short* gl = Wl + (size_t)n*Hh;
  char* rowp = L + r*1024;
  #pragma unroll
  for (int u = 0; u < 16; ++u) {
    const int s = q*16 + u;
    const int so = (s ^ (r & 7)) * 16;
    *(uint4*)(rowp + so)         = *(const uint4*)(gh + s*8);
    *(uint4*)(rowp + 65536 + so) = *(const uint4*)(gl + s*8);
  }
  __syncthreads();
}
// role B: one matrix slab: 32 rows (g = r>>3, j = r&7), hi 32KB then lo 32KB
__device__ void stageB_w(const unsigned short* Wh, const unsigned short* Wl, int j0, char* slab) {
  const int t = threadIdx.x;
  const int r = t >> 3, q = t & 7;
  const int n = (r >> 3)*Hh + j0 + (r & 7);
  const unsigned short* gh = Wh + (size_t)n*Hh;
  const unsigned short* gl = Wl + (size_t)n*Hh;
  char* rowp = slab + r*1024;
  #pragma unroll
  for (int u = 0; u < 8; ++u) {
    const int s = q*8 + u;
    const int so = (s ^ (r & 7)) * 16;
    *(uint4*)(rowp + so)         = *(const uint4*)(gh + s*8);
    *(uint4*)(rowp + 32768 + so) = *(const uint4*)(gl + s*8);
  }
  __syncthreads();
}

// ---- role A cell step: 64 rows x (4 gates x 16 j), W in LDS ----
__device__ __forceinline__ void stepA(const KP& kp, const char* L, float* sS,
    int m0, int j0, int jg,
    const unsigned short* Ah, const unsigned short* Al,
    const float* sW, const float* bias, float* cst,
    unsigned short* Ho, unsigned short* Lo,
    int smode, int sarg)
{
  const int tid = threadIdx.x;
  if (smode == 0) {
    if (tid < 64) sS[tid] = kp.x[(size_t)(m0 + tid)*Tt + sarg];
  } else {
    const int bl = tid >> 2, part = tid & 3;
    const int b = m0 + bl;
    float a = 0.f;
    #pragma unroll
    for (int u = 0; u < 16; ++u) a += kp.pred[(part*16 + u)*Bb + b];
    a += __shfl_xor(a, 1, 64);
    a += __shfl_xor(a, 2, 64);
    const float s = a + kp.linb[0];
    if (part == 0) {
      sS[bl] = s;
      if (jg == 0 && sarg >= 1) kp.out[(size_t)b*NPR + (sarg - 1)] = s;
    }
  }
  __syncthreads();

  const int wv = tid >> 6, lane = tid & 63;
  const int r15 = lane & 15, kg = lane >> 4;
  f4 acc[4];
  #pragma unroll
  for (int g = 0; g < 4; ++g) acc[g] = (f4){0.f,0.f,0.f,0.f};
  const size_t ab = (size_t)(m0 + wv*16 + r15)*Hh + kg*8;
  const int swz = r15 & 7;
  #pragma unroll 4
  for (int ks = 0; ks < 16; ++ks) {
    const bf8 a_h = *(const bf8*)(Ah + ab + ks*32);
    const bf8 a_l = *(const bf8*)(Al + ab + ks*32);
    const int so = ((ks*4 + kg) ^ swz) * 16;
    #pragma unroll
    for (int g = 0; g < 4; ++g) {
      const int ro = (g*16 + r15)*1024 + so;
      const bf8 w_h = *(const bf8*)(L + ro);
      const bf8 w_l = *(const bf8*)(L + 65536 + ro);
      MF(a_h, w_h, acc[g]);
      MF(a_l, w_h, acc[g]);
      MF(a_h, w_l, acc[g]);
    }
  }
  const int j = j0 + r15;
  const float sw0 = sW[j], sw1 = sW[Hh+j], sw2 = sW[2*Hh+j], sw3 = sW[3*Hh+j];
  const float bi = bias[j], bfv = bias[Hh+j], bgv = bias[2*Hh+j], bo = bias[3*Hh+j];
  #pragma unroll
  for (int r = 0; r < 4; ++r) {
    const int bloc = wv*16 + kg*4 + r;
    const float sv = sS[bloc];
    const size_t idx = (size_t)(m0 + bloc)*Hh + j;
    const float gi = acc[0][r] + bi  + sv*sw0;
    const float gf = acc[1][r] + bfv + sv*sw1;
    const float gg = acc[2][r] + bgv + sv*sw2;
    const float go = acc[3][r] + bo  + sv*sw3;
    const float si = 1.f/(1.f + expf(-gi));
    const float sf = 1.f/(1.f + expf(-gf));
    const float so_ = 1.f/(1.f + expf(-go));
    const float c2 = sf * cst[idx] + si * tanhf(gg);
    const float h2 = so_ * tanhf(c2);
    cst[idx] = c2;
    const unsigned short hh2 = f2bf(h2);
    Ho[idx] = hh2;
    Lo[idx] = f2bf(h2 - bf2f(hh2));
  }
}

// ---- role B cell step: 128 rows x (4 gates x 8 j), 2 GEMMs, W in LDS ----
__device__ __forceinline__ void stepB(const KP& kp, const char* L,
    int m0, int j0, int jg,
    const unsigned short* A1h, const unsigned short* A1l,   // h1 prev
    const unsigned short* A2h, const unsigned short* A2l,   // h0 current
    const float* bias, float* cst,
    unsigned short* Ho, unsigned short* Lo, int doPred)
{
  const int tid = threadIdx.x, wv = tid >> 6, lane = tid & 63;
  const int r15 = lane & 15, kg = lane >> 4;
  f4 acc[2][2];
  acc[0][0] = acc[0][1] = acc[1][0] = acc[1][1] = (f4){0.f,0.f,0.f,0.f};
  const int swz = r15 & 7;
  const size_t ab0 = (size_t)(m0 + wv*32 + r15)*Hh + kg*8;
  const size_t ab1 = ab0 + (size_t)16*Hh;
  #pragma unroll
  for (int gm = 0; gm < 2; ++gm) {
    const unsigned short* Ah = gm ? A1h : A2h;   // slab0=Wih1(x=h0), slab1=Whh1(h1)
    const unsigned short* Al = gm ? A1l : A2l;
    const char* Wh = L + gm*65536;
    const char* Wl = Wh + 32768;
    #pragma unroll 4
    for (int ks = 0; ks < 16; ++ks) {
      const bf8 a0h = *(const bf8*)(Ah + ab0 + ks*32);
      const bf8 a0l = *(const bf8*)(Al + ab0 + ks*32);
      const bf8 a1h = *(const bf8*)(Ah + ab1 + ks*32);
      const bf8 a1l = *(const bf8*)(Al + ab1 + ks*32);
      const int so = ((ks*4 + kg) ^ swz) * 16;
      const bf8 w0h = *(const bf8*)(Wh + r15*1024 + so);
      const bf8 w1h = *(const bf8*)(Wh + (16 + r15)*1024 + so);
      const bf8 w0l = *(const bf8*)(Wl + r15*1024 + so);
      const bf8 w1l = *(const bf8*)(Wl + (16 + r15)*1024 + so);
      MF(a0h, w0h, acc[0][0]); MF(a0l, w0h, acc[0][0]); MF(a0h, w0l, acc[0][0]);
      MF(a0h, w1h, acc[0][1]); MF(a0l, w1h, acc[0][1]); MF(a0h, w1l, acc[0][1]);
      MF(a1h, w0h, acc[1][0]); MF(a1l, w0h, acc[1][0]); MF(a1h, w0l, acc[1][0]);
      MF(a1h, w1h, acc[1][1]); MF(a1l, w1h, acc[1][1]); MF(a1h, w1l, acc[1][1]);
    }
  }
  // lane^8 exchange: gather all 4 gates for my (b,j)
  float og[2][2][4];
  #pragma unroll
  for (int m = 0; m < 2; ++m)
    #pragma unroll
    for (int t = 0; t < 2; ++t)
      #pragma unroll
      for (int c = 0; c < 4; ++c)
        og[m][t][c] = __shfl_xor(acc[m][t][c], 8, 64);
  const int bit = r15 >> 3;     // my gate-bit; also the m-sub I epilogue
  float gv[4][4];
  #pragma unroll
  for (int g = 0; g < 4; ++g)
    #pragma unroll
    for (int c = 0; c < 4; ++c) {
      const float mine = bit ? acc[1][g>>1][c] : acc[0][g>>1][c];
      const float oth  = bit ? og[1][g>>1][c]  : og[0][g>>1][c];
      gv[g][c] = ((g & 1) == bit) ? mine : oth;
    }
  const int j = j0 + (r15 & 7);
  const float bi = bias[j], bfv = bias[Hh+j], bgv = bias[2*Hh+j], bo = bias[3*Hh+j];
  float hs[4];
  #pragma unroll
  for (int r = 0; r < 4; ++r) {
    const int b = m0 + wv*32 + bit*16 + kg*4 + r;
    const size_t idx = (size_t)b*Hh + j;
    const float gi = gv[0][r] + bi;
    const float gf = gv[1][r] + bfv;
    const float gg = gv[2][r] + bgv;
    const float go = gv[3][r] + bo;
    const float si = 1.f/(1.f + expf(-gi));
    const float sf = 1.f/(1.f + expf(-gf));
    const float so_ = 1.f/(1.f + expf(-go));
    const float c2 = sf * cst[idx] + si * tanhf(gg);
    const float h2 = so_ * tanhf(c2);
    cst[idx] = c2;
    const unsigned short hh2 = f2bf(h2);
    Ho[idx] = hh2;
    Lo[idx] = f2bf(h2 - bf2f(hh2));
    hs[r] = h2;
  }
  if (doPred) {
    const float lw = kp.linW[j];
    #pragma unroll
    for (int r = 0; r < 4; ++r) {
      float p = hs[r] * lw;
      p += __shfl_xor(p, 1, 64);
      p += __shfl_xor(p, 2, 64);
      p += __shfl_xor(p, 4, 64);
      if ((r15 & 7) == 0)
        kp.pred[jg*Bb + (m0 + wv*32 + bit*16 + kg*4 + r)] = p;
    }
  }
}

#define PH0(p) ((p) ? kp.h0h1 : kp.h0h0)
#define PL0(p) ((p) ? kp.h0l1 : kp.h0l0)
#define PH1(p) ((p) ? kp.h1h1 : kp.h1h0)
#define PL1(p) ((p) ? kp.h1l1 : kp.h1l0)

__global__ __launch_bounds__(256, 1) void lstm_persist(KP kp) {
  extern __shared__ char L[];
  float* sS = (float*)(L + 131072);
  const int blk = blockIdx.x;
  const bool roleA = blk < 128;
  int m0, j0, jg;
  if (roleA) { jg = blk >> 2; m0 = (blk & 3) * 64; j0 = jg * 16; }
  else { const int b2 = blk - 128; jg = b2 >> 1; m0 = (b2 & 1) * 128; j0 = jg * 8; }

  if (roleA) stageA_w(kp.eWhh0h, kp.eWhh0l, j0, L);
  else { stageB_w(kp.eWih1h, kp.eWih1l, j0, L); stageB_w(kp.eWhh1h, kp.eWhh1l, j0, L + 65536); }

  // ---- encoder: stage s = L0(t=s) || L1(t=s-1) ----
  for (int s = 0; s <= Tt; ++s) {
    if (roleA) {
      if (s < Tt)
        stepA(kp, L, sS, m0, j0, jg, PH0(s&1), PL0(s&1), kp.eWih0, kp.eb0,
              kp.c0, PH0((s+1)&1), PL0((s+1)&1), 0, s);
    } else {
      if (s >= 1)
        stepB(kp, L, m0, j0, jg, PH1((s-1)&1), PL1((s-1)&1), PH0(s&1), PL0(s&1),
              kp.eb1, kp.c1, PH1(s&1), PL1(s&1), 0);
    }
    gsync(kp.bar);
  }

  // ---- transition: restage decoder weights ----
  if (roleA) stageA_w(kp.dWhh0h, kp.dWhh0l, j0, L);
  else { stageB_w(kp.dWih1h, kp.dWih1l, j0, L); stageB_w(kp.dWhh1h, kp.dWhh1l, j0, L + 65536); }

  // ---- decoder: 128 steps, 2 sub-stages each ----
  for (int i = 0; i < NPR; ++i) {
    if (roleA) {
      if (i == 0)
        stepA(kp, L, sS, m0, j0, jg, PH0(0), PL0(0), kp.dWih0, kp.db0,
              kp.c0, PH0(1), PL0(1), 0, Tt - 1);
      else
        stepA(kp, L, sS, m0, j0, jg, PH0(i&1), PL0(i&1), kp.dWih0, kp.db0,
              kp.c0, PH0((i+1)&1), PL0((i+1)&1), 1, i);
    }
    gsync(kp.bar);
    if (!roleA)
      stepB(kp, L, m0, j0, jg, PH1(i&1), PL1(i&1), PH0((i+1)&1), PL0((i+1)&1),
            kp.db1, kp.c1, PH1((i+1)&1), PL1((i+1)&1), 1);
    gsync(kp.bar);
  }

  // ---- tail: out[:,127] ----
  if (roleA && jg == 0) {
    const int tid = threadIdx.x, bl = tid >> 2, part = tid & 3, b = m0 + bl;
    float a = 0.f;
    #pragma unroll
    for (int u = 0; u < 16; ++u) a += kp.pred[(part*16 + u)*Bb + b];
    a += __shfl_xor(a, 1, 64);
    a += __shfl_xor(a, 2, 64);
    if (part == 0) kp.out[(size_t)b*NPR + 127] = a + kp.linb[0];
  }
}

__global__ __launch_bounds__(256) void conv_w(const float* __restrict__ src,
                                              unsigned short* __restrict__ hi,
                                              unsigned short* __restrict__ lo) {
  const int i = (blockIdx.x * 256 + threadIdx.x) * 4;
  const float4 v = *(const float4*)(src + i);
  const unsigned short h0 = f2bf(v.x), h1 = f2bf(v.y), h2 = f2bf(v.z), h3 = f2bf(v.w);
  ushort4 hv; hv.x = h0; hv.y = h1; hv.z = h2; hv.w = h3;
  ushort4 lv;
  lv.x = f2bf(v.x - bf2f(h0)); lv.y = f2bf(v.y - bf2f(h1));
  lv.z = f2bf(v.z - bf2f(h2)); lv.w = f2bf(v.w - bf2f(h3));
  *(ushort4*)(hi + i) = hv;
  *(ushort4*)(lo + i) = lv;
}

extern "C" void kernel_launch(void* const* d_in, const int* in_sizes, int n_in,
                              void* d_out, int out_size, void* d_ws, size_t ws_size,
                              hipStream_t stream) {
  const float* x     = (const float*)d_in[0];
  const float* eWih0 = (const float*)d_in[1];
  const float* eWhh0 = (const float*)d_in[2];
  const float* eb0   = (const float*)d_in[3];
  const float* eWih1 = (const float*)d_in[4];
  const float* eWhh1 = (const float*)d_in[5];
  const float* eb1   = (const float*)d_in[6];
  const float* dWih0 = (const float*)d_in[7];
  const float* dWhh0 = (const float*)d_in[8];
  const float* db0   = (const float*)d_in[9];
  const float* dWih1 = (const float*)d_in[10];
  const float* dWhh1 = (const float*)d_in[11];
  const float* db1   = (const float*)d_in[12];
  const float* linW  = (const float*)d_in[13];
  const float* linb  = (const float*)d_in[14];
  float* out = (float*)d_out;

  unsigned short* wb = (unsigned short*)d_ws;
  unsigned short* W[12];
  for (int k = 0; k < 12; ++k) W[k] = wb + (size_t)k*WN;
  unsigned short* sb = wb + (size_t)12*WN;   // 8 h buffers
  float* cb   = (float*)(sb + (size_t)8*BH);
  float* c0   = cb;
  float* c1   = cb + BH;
  float* pred = cb + 2*(size_t)BH;           // 64*256 floats
  unsigned* bar = (unsigned*)(pred + 64*Bb);

  (void)hipMemsetAsync(sb + 0*(size_t)BH, 0, (size_t)BH*2, stream); // h0h[0]
  (void)hipMemsetAsync(sb + 2*(size_t)BH, 0, (size_t)BH*2, stream); // h0l[0]
  (void)hipMemsetAsync(sb + 4*(size_t)BH, 0, (size_t)BH*2, stream); // h1h[0]
  (void)hipMemsetAsync(sb + 6*(size_t)BH, 0, (size_t)BH*2, stream); // h1l[0]
  (void)hipMemsetAsync(c0, 0, (size_t)BH*4, stream);
  (void)hipMemsetAsync(c1, 0, (size_t)BH*4, stream);
  (void)hipMemsetAsync(bar, 0, 2048, stream);

  conv_w<<<1024, 256, 0, stream>>>(eWhh0, W[0], W[1]);
  conv_w<<<1024, 256, 0, stream>>>(eWih1, W[2], W[3]);
  conv_w<<<1024, 256, 0, stream>>>(eWhh1, W[4], W[5]);
  conv_w<<<1024, 256, 0, stream>>>(dWhh0, W[6], W[7]);
  conv_w<<<1024, 256, 0, stream>>>(dWih1, W[8], W[9]);
  conv_w<<<1024, 256, 0, stream>>>(dWhh1, W[10], W[11]);

  KP kp;
  kp.x = x; kp.eb0 = eb0; kp.eb1 = eb1; kp.db0 = db0; kp.db1 = db1;
  kp.eWih0 = eWih0; kp.dWih0 = dWih0; kp.linW = linW; kp.linb = linb;
  kp.eWhh0h = W[0]; kp.eWhh0l = W[1];
  kp.eWih1h = W[2]; kp.eWih1l = W[3];
  kp.eWhh1h = W[4]; kp.eWhh1l = W[5];
  kp.dWhh0h = W[6]; kp.dWhh0l = W[7];
  kp.dWih1h = W[8]; kp.dWih1l = W[9];
  kp.dWhh1h = W[10]; kp.dWhh1l = W[11];
  kp.h0h0 = sb + 0*(size_t)BH; kp.h0h1 = sb + 1*(size_t)BH;
  kp.h0l0 = sb + 2*(size_t)BH; kp.h0l1 = sb + 3*(size_t)BH;
  kp.h1h0 = sb + 4*(size_t)BH; kp.h1h1 = sb + 5*(size_t)BH;
  kp.h1l0 = sb + 6*(size_t)BH; kp.h1l1 = sb + 7*(size_t)BH;
  kp.c0 = c0; kp.c1 = c1; kp.pred = pred; kp.out = out; kp.bar = bar;

  (void)hipFuncSetAttribute((const void*)lstm_persist,
                            hipFuncAttributeMaxDynamicSharedMemorySize, LDSB);
  void* kargs[] = { (void*)&kp };
  (void)hipLaunchCooperativeKernel((const void*)lstm_persist, dim3(256), dim3(256),
                                   kargs, LDSB, stream);
  (void)in_sizes; (void)n_in; (void)out_size; (void)ws_size;
}

// Round 7
// 41020.554 us; speedup vs baseline: 1.7800x; 1.7800x over previous
//
#include <hip/hip_runtime.h>

#define Hh 512
#define Bb 256
#define Tt 512
#define NPR 128
#define BH (Bb*Hh)
#define WN (4*Hh*Hh)
#define LDSB (131072 + 256)

typedef __attribute__((ext_vector_type(8))) short bf8;
typedef __attribute__((ext_vector_type(4))) float f4;

#define MF(A,B,C) C = __builtin_amdgcn_mfma_f32_16x16x32_bf16(A,B,C,0,0,0)

__device__ __forceinline__ unsigned short f2bf(float x) {
  unsigned u = __float_as_uint(x);
  return (unsigned short)((u + 0x7FFFu + ((u >> 16) & 1u)) >> 16);
}
__device__ __forceinline__ float bf2f(unsigned short h) {
  return __uint_as_float((unsigned)h << 16);
}

struct KP {
  const float *x, *eb0, *eb1, *db0, *db1, *eWih0, *dWih0, *linW, *linb;
  const unsigned short *eWhh0h,*eWhh0l,*eWih1h,*eWih1l,*eWhh1h,*eWhh1l;
  const unsigned short *dWhh0h,*dWhh0l,*dWih1h,*dWih1l,*dWhh1h,*dWhh1l;
  unsigned short *h0h0,*h0h1,*h0l0,*h0l1,*h1h0,*h1h1,*h1l0,*h1l1;
  float *c0,*c1,*pred,*out;
  unsigned *bar;
};

// ---- grid barrier: monotonic counters, RELAXED atomics (no per-poll cache ops),
// ---- one release fence before arrive + one acquire fence after release observed.
__device__ void gsync(unsigned* bar, unsigned rnd) {
  __syncthreads();
  __threadfence();            // release: writeback dirty lines (once per barrier)
  if (threadIdx.x == 0) {
    const int grp = blockIdx.x >> 4;
    const unsigned a = __hip_atomic_fetch_add(bar + grp*16, 1u, __ATOMIC_RELAXED, __HIP_MEMORY_SCOPE_AGENT);
    if (a == rnd*16u + 15u) {
      const unsigned r = __hip_atomic_fetch_add(bar + 256, 1u, __ATOMIC_RELAXED, __HIP_MEMORY_SCOPE_AGENT);
      if (r == rnd*16u + 15u)
        __hip_atomic_store(bar + 272, rnd + 1u, __ATOMIC_RELAXED, __HIP_MEMORY_SCOPE_AGENT);
    }
    while (__hip_atomic_load(bar + 272, __ATOMIC_RELAXED, __HIP_MEMORY_SCOPE_AGENT) <= rnd)
      __builtin_amdgcn_s_sleep(8);
  }
  __syncthreads();
  __threadfence();            // acquire: invalidate stale caches (once per barrier)
}

// ---- one-time weight staging into LDS (XOR-swizzled 16B slots) ----
__device__ void stageA_w(const unsigned short* Wh, const unsigned short* Wl, int j0, char* L) {
  const int t = threadIdx.x;
  const int r = t >> 2, q = t & 3;
  const int n = (r >> 4)*Hh + j0 + (r & 15);
  const unsigned short* gh = Wh + (size_t)n*Hh;
  const unsigned short* gl = Wl + (size_t)n*Hh;
  char* rowp = L + r*1024;
  #pragma unroll
  for (int u = 0; u < 16; ++u) {
    const int s = q*16 + u;
    const int so = (s ^ (r & 7)) * 16;
    *(uint4*)(rowp + so)         = *(const uint4*)(gh + s*8);
    *(uint4*)(rowp + 65536 + so) = *(const uint4*)(gl + s*8);
  }
  __syncthreads();
}
__device__ void stageB_w(const unsigned short* Wh, const unsigned short* Wl, int j0, char* slab) {
  const int t = threadIdx.x;
  const int r = t >> 3, q = t & 7;
  const int n = (r >> 3)*Hh + j0 + (r & 7);
  const unsigned short* gh = Wh + (size_t)n*Hh;
  const unsigned short* gl = Wl + (size_t)n*Hh;
  char* rowp = slab + r*1024;
  #pragma unroll
  for (int u = 0; u < 8; ++u) {
    const int s = q*8 + u;
    const int so = (s ^ (r & 7)) * 16;
    *(uint4*)(rowp + so)         = *(const uint4*)(gh + s*8);
    *(uint4*)(rowp + 32768 + so) = *(const uint4*)(gl + s*8);
  }
  __syncthreads();
}

// ---- role A cell step: 64 rows x (4 gates x 16 j), W in LDS, c in global ----
__device__ __forceinline__ void stepA(const KP& kp, const char* L, float* sS,
    int m0, int j0, int jg,
    const unsigned short* Ah, const unsigned short* Al,
    const float* sW, const float* bias, float* cst,
    unsigned short* Ho, unsigned short* Lo,
    int smode, int sarg)
{
  const int tid = threadIdx.x;
  if (smode == 0) {
    if (tid < 64) sS[tid] = kp.x[(size_t)(m0 + tid)*Tt + sarg];
  } else {
    const int bl = tid >> 2, part = tid & 3;
    const int b = m0 + bl;
    float a = 0.f;
    #pragma unroll
    for (int u = 0; u < 16; ++u) a += kp.pred[(part*16 + u)*Bb + b];
    a += __shfl_xor(a, 1, 64);
    a += __shfl_xor(a, 2, 64);
    const float s = a + kp.linb[0];
    if (part == 0) {
      sS[bl] = s;
      if (jg == 0 && sarg >= 1) kp.out[(size_t)b*NPR + (sarg - 1)] = s;
    }
  }
  __syncthreads();

  const int wv = tid >> 6, lane = tid & 63;
  const int r15 = lane & 15, kg = lane >> 4;
  f4 acc[4];
  #pragma unroll
  for (int g = 0; g < 4; ++g) acc[g] = (f4){0.f,0.f,0.f,0.f};
  const size_t ab = (size_t)(m0 + wv*16 + r15)*Hh + kg*8;
  const int swz = r15 & 7;

  #pragma unroll
  for (int half = 0; half < 2; ++half) {
    bf8 ahv[8], alv[8];
    #pragma unroll
    for (int q = 0; q < 8; ++q) {          // burst: 16 loads in flight
      const int ks = half*8 + q;
      ahv[q] = *(const bf8*)(Ah + ab + ks*32);
      alv[q] = *(const bf8*)(Al + ab + ks*32);
    }
    #pragma unroll
    for (int q = 0; q < 8; ++q) {
      const int ks = half*8 + q;
      const int so = ((ks*4 + kg) ^ swz) * 16;
      #pragma unroll
      for (int g = 0; g < 4; ++g) {
        const int ro = (g*16 + r15)*1024 + so;
        const bf8 w_h = *(const bf8*)(L + ro);
        const bf8 w_l = *(const bf8*)(L + 65536 + ro);
        MF(ahv[q], w_h, acc[g]);
        MF(alv[q], w_h, acc[g]);
        MF(ahv[q], w_l, acc[g]);
      }
    }
  }

  const int j = j0 + r15;
  const float sw0 = sW[j], sw1 = sW[Hh+j], sw2 = sW[2*Hh+j], sw3 = sW[3*Hh+j];
  const float bi = bias[j], bfv = bias[Hh+j], bgv = bias[2*Hh+j], bo = bias[3*Hh+j];
  #pragma unroll
  for (int r = 0; r < 4; ++r) {
    const int bloc = wv*16 + kg*4 + r;
    const float sv = sS[bloc];
    const size_t idx = (size_t)(m0 + bloc)*Hh + j;
    const float gi = acc[0][r] + bi  + sv*sw0;
    const float gf = acc[1][r] + bfv + sv*sw1;
    const float gg = acc[2][r] + bgv + sv*sw2;
    const float go = acc[3][r] + bo  + sv*sw3;
    const float si = 1.f/(1.f + expf(-gi));
    const float sf = 1.f/(1.f + expf(-gf));
    const float so_ = 1.f/(1.f + expf(-go));
    const float c2 = sf * cst[idx] + si * tanhf(gg);
    const float h2 = so_ * tanhf(c2);
    cst[idx] = c2;
    const unsigned short hh2 = f2bf(h2);
    Ho[idx] = hh2;
    Lo[idx] = f2bf(h2 - bf2f(hh2));
  }
}

// ---- role B cell step: 128 rows x (4 gates x 8 j), 2 GEMMs, W in LDS ----
__device__ __forceinline__ void stepB(const KP& kp, const char* L,
    int m0, int j0, int jg,
    const unsigned short* A1h, const unsigned short* A1l,   // h1 prev
    const unsigned short* A2h, const unsigned short* A2l,   // h0 current
    const float* bias, float* cst,
    unsigned short* Ho, unsigned short* Lo, int doPred)
{
  const int tid = threadIdx.x, wv = tid >> 6, lane = tid & 63;
  const int r15 = lane & 15, kg = lane >> 4;
  f4 acc[2][2];
  acc[0][0] = acc[0][1] = acc[1][0] = acc[1][1] = (f4){0.f,0.f,0.f,0.f};
  const int swz = r15 & 7;
  #pragma unroll
  for (int gm = 0; gm < 2; ++gm) {
    const unsigned short* Ah = gm ? A1h : A2h;   // slab0=Wih1(x=h0), slab1=Whh1(h1)
    const unsigned short* Al = gm ? A1l : A2l;
    const char* Wh = L + gm*65536;
    const char* Wl = Wh + 32768;
    #pragma unroll
    for (int mr = 0; mr < 2; ++mr) {
      const size_t ab = (size_t)(m0 + wv*32 + mr*16 + r15)*Hh + kg*8;
      #pragma unroll
      for (int half = 0; half < 2; ++half) {
        bf8 ahv[8], alv[8];
        #pragma unroll
        for (int q = 0; q < 8; ++q) {       // burst: 16 loads in flight
          const int ks = half*8 + q;
          ahv[q] = *(const bf8*)(Ah + ab + ks*32);
          alv[q] = *(const bf8*)(Al + ab + ks*32);
        }
        #pragma unroll
        for (int q = 0; q < 8; ++q) {
          const int ks = half*8 + q;
          const int so = ((ks*4 + kg) ^ swz) * 16;
          const bf8 w0h = *(const bf8*)(Wh + r15*1024 + so);
          const bf8 w1h = *(const bf8*)(Wh + (16 + r15)*1024 + so);
          const bf8 w0l = *(const bf8*)(Wl + r15*1024 + so);
          const bf8 w1l = *(const bf8*)(Wl + (16 + r15)*1024 + so);
          MF(ahv[q], w0h, acc[mr][0]); MF(alv[q], w0h, acc[mr][0]); MF(ahv[q], w0l, acc[mr][0]);
          MF(ahv[q], w1h, acc[mr][1]); MF(alv[q], w1h, acc[mr][1]); MF(ahv[q], w1l, acc[mr][1]);
        }
      }
    }
  }
  // lane^8 exchange: gather all 4 gates for my (b,j)
  float og[2][2][4];
  #pragma unroll
  for (int m = 0; m < 2; ++m)
    #pragma unroll
    for (int t = 0; t < 2; ++t)
      #pragma unroll
      for (int c = 0; c < 4; ++c)
        og[m][t][c] = __shfl_xor(acc[m][t][c], 8, 64);
  const int bit = r15 >> 3;
  float gv[4][4];
  #pragma unroll
  for (int g = 0; g < 4; ++g)
    #pragma unroll
    for (int c = 0; c < 4; ++c) {
      const float mine = bit ? acc[1][g>>1][c] : acc[0][g>>1][c];
      const float oth  = bit ? og[1][g>>1][c]  : og[0][g>>1][c];
      gv[g][c] = ((g & 1) == bit) ? mine : oth;
    }
  const int j = j0 + (r15 & 7);
  const float bi = bias[j], bfv = bias[Hh+j], bgv = bias[2*Hh+j], bo = bias[3*Hh+j];
  float hs[4];
  #pragma unroll
  for (int r = 0; r < 4; ++r) {
    const int bl = wv*32 + bit*16 + kg*4 + r;
    const size_t idx = (size_t)(m0 + bl)*Hh + j;
    const float gi = gv[0][r] + bi;
    const float gf = gv[1][r] + bfv;
    const float gg = gv[2][r] + bgv;
    const float go = gv[3][r] + bo;
    const float si = 1.f/(1.f + expf(-gi));
    const float sf = 1.f/(1.f + expf(-gf));
    const float so_ = 1.f/(1.f + expf(-go));
    const float c2 = sf * cst[idx] + si * tanhf(gg);
    const float h2 = so_ * tanhf(c2);
    cst[idx] = c2;
    const unsigned short hh2 = f2bf(h2);
    Ho[idx] = hh2;
    Lo[idx] = f2bf(h2 - bf2f(hh2));
    hs[r] = h2;
  }
  if (doPred) {
    const float lw = kp.linW[j];
    #pragma unroll
    for (int r = 0; r < 4; ++r) {
      float p = hs[r] * lw;
      p += __shfl_xor(p, 1, 64);
      p += __shfl_xor(p, 2, 64);
      p += __shfl_xor(p, 4, 64);
      if ((r15 & 7) == 0)
        kp.pred[jg*Bb + (m0 + wv*32 + bit*16 + kg*4 + r)] = p;
    }
  }
}

#define PH0(p) ((p) ? kp.h0h1 : kp.h0h0)
#define PL0(p) ((p) ? kp.h0l1 : kp.h0l0)
#define PH1(p) ((p) ? kp.h1h1 : kp.h1h0)
#define PL1(p) ((p) ? kp.h1l1 : kp.h1l0)

__global__ __launch_bounds__(256, 1) void lstm_persist(KP kp) {
  extern __shared__ char L[];
  float* sS = (float*)(L + 131072);
  const int blk = blockIdx.x;
  const bool roleA = blk < 128;
  int m0, j0, jg;
  if (roleA) { jg = blk >> 2; m0 = (blk & 3) * 64; j0 = jg * 16; }
  else { const int b2 = blk - 128; jg = b2 >> 1; m0 = (b2 & 1) * 128; j0 = jg * 8; }

  if (roleA) stageA_w(kp.eWhh0h, kp.eWhh0l, j0, L);
  else { stageB_w(kp.eWih1h, kp.eWih1l, j0, L); stageB_w(kp.eWhh1h, kp.eWhh1l, j0, L + 65536); }

  unsigned rnd = 0;

  // ---- encoder: stage s = L0(t=s) || L1(t=s-1) ----
  for (int s = 0; s <= Tt; ++s) {
    if (roleA) {
      if (s < Tt)
        stepA(kp, L, sS, m0, j0, jg, PH0(s&1), PL0(s&1), kp.eWih0, kp.eb0,
              kp.c0, PH0((s+1)&1), PL0((s+1)&1), 0, s);
    } else {
      if (s >= 1)
        stepB(kp, L, m0, j0, jg, PH1((s-1)&1), PL1((s-1)&1), PH0(s&1), PL0(s&1),
              kp.eb1, kp.c1, PH1(s&1), PL1(s&1), 0);
    }
    gsync(kp.bar, rnd++);
  }

  // ---- transition: restage decoder weights ----
  if (roleA) stageA_w(kp.dWhh0h, kp.dWhh0l, j0, L);
  else { stageB_w(kp.dWih1h, kp.dWih1l, j0, L); stageB_w(kp.dWhh1h, kp.dWhh1l, j0, L + 65536); }

  // ---- decoder: 128 steps, 2 sub-stages each ----
  for (int i = 0; i < NPR; ++i) {
    if (roleA) {
      if (i == 0)
        stepA(kp, L, sS, m0, j0, jg, PH0(0), PL0(0), kp.dWih0, kp.db0,
              kp.c0, PH0(1), PL0(1), 0, Tt - 1);
      else
        stepA(kp, L, sS, m0, j0, jg, PH0(i&1), PL0(i&1), kp.dWih0, kp.db0,
              kp.c0, PH0((i+1)&1), PL0((i+1)&1), 1, i);
    }
    gsync(kp.bar, rnd++);
    if (!roleA)
      stepB(kp, L, m0, j0, jg, PH1(i&1), PL1(i&1), PH0((i+1)&1), PL0((i+1)&1),
            kp.db1, kp.c1, PH1((i+1)&1), PL1((i+1)&1), 1);
    gsync(kp.bar, rnd++);
  }

  // ---- tail: out[:,127] ----
  if (roleA && jg == 0) {
    const int tid = threadIdx.x, bl = tid >> 2, part = tid & 3, b = m0 + bl;
    float a = 0.f;
    #pragma unroll
    for (int u = 0; u < 16; ++u) a += kp.pred[(part*16 + u)*Bb + b];
    a += __shfl_xor(a, 1, 64);
    a += __shfl_xor(a, 2, 64);
    if (part == 0) kp.out[(size_t)b*NPR + 127] = a + kp.linb[0];
  }
}

__global__ __launch_bounds__(256) void conv_w(const float* __restrict__ src,
                                              unsigned short* __restrict__ hi,
                                              unsigned short* __restrict__ lo) {
  const int i = (blockIdx.x * 256 + threadIdx.x) * 4;
  const float4 v = *(const float4*)(src + i);
  const unsigned short h0 = f2bf(v.x), h1 = f2bf(v.y), h2 = f2bf(v.z), h3 = f2bf(v.w);
  ushort4 hv; hv.x = h0; hv.y = h1; hv.z = h2; hv.w = h3;
  ushort4 lv;
  lv.x = f2bf(v.x - bf2f(h0)); lv.y = f2bf(v.y - bf2f(h1));
  lv.z = f2bf(v.z - bf2f(h2)); lv.w = f2bf(v.w - bf2f(h3));
  *(ushort4*)(hi + i) = hv;
  *(ushort4*)(lo + i) = lv;
}

extern "C" void kernel_launch(void* const* d_in, const int* in_sizes, int n_in,
                              void* d_out, int out_size, void* d_ws, size_t ws_size,
                              hipStream_t stream) {
  const float* x     = (const float*)d_in[0];
  const float* eWih0 = (const float*)d_in[1];
  const float* eWhh0 = (const float*)d_in[2];
  const float* eb0   = (const float*)d_in[3];
  const float* eWih1 = (const float*)d_in[4];
  const float* eWhh1 = (const float*)d_in[5];
  const float* eb1   = (const float*)d_in[6];
  const float* dWih0 = (const float*)d_in[7];
  const float* dWhh0 = (const float*)d_in[8];
  const float* db0   = (const float*)d_in[9];
  const float* dWih1 = (const float*)d_in[10];
  const float* dWhh1 = (const float*)d_in[11];
  const float* db1   = (const float*)d_in[12];
  const float* linW  = (const float*)d_in[13];
  const float* linb  = (const float*)d_in[14];
  float* out = (float*)d_out;

  unsigned short* wb = (unsigned short*)d_ws;
  unsigned short* W[12];
  for (int k = 0; k < 12; ++k) W[k] = wb + (size_t)k*WN;
  unsigned short* sb = wb + (size_t)12*WN;   // 8 h buffers
  float* cb   = (float*)(sb + (size_t)8*BH);
  float* c0   = cb;
  float* c1   = cb + BH;
  float* pred = cb + 2*(size_t)BH;           // 64*256 floats
  unsigned* bar = (unsigned*)(pred + 64*Bb);

  (void)hipMemsetAsync(sb + 0*(size_t)BH, 0, (size_t)BH*2, stream); // h0h[0]
  (void)hipMemsetAsync(sb + 2*(size_t)BH, 0, (size_t)BH*2, stream); // h0l[0]
  (void)hipMemsetAsync(sb + 4*(size_t)BH, 0, (size_t)BH*2, stream); // h1h[0]
  (void)hipMemsetAsync(sb + 6*(size_t)BH, 0, (size_t)BH*2, stream); // h1l[0]
  (void)hipMemsetAsync(c0, 0, (size_t)BH*4, stream);
  (void)hipMemsetAsync(c1, 0, (size_t)BH*4, stream);
  (void)hipMemsetAsync(bar, 0, 2048, stream);

  conv_w<<<1024, 256, 0, stream>>>(eWhh0, W[0], W[1]);
  conv_w<<<1024, 256, 0, stream>>>(eWih1, W[2], W[3]);
  conv_w<<<1024, 256, 0, stream>>>(eWhh1, W[4], W[5]);
  conv_w<<<1024, 256, 0, stream>>>(dWhh0, W[6], W[7]);
  conv_w<<<1024, 256, 0, stream>>>(dWih1, W[8], W[9]);
  conv_w<<<1024, 256, 0, stream>>>(dWhh1, W[10], W[11]);

  KP kp;
  kp.x = x; kp.eb0 = eb0; kp.eb1 = eb1; kp.db0 = db0; kp.db1 = db1;
  kp.eWih0 = eWih0; kp.dWih0 = dWih0; kp.linW = linW; kp.linb = linb;
  kp.eWhh0h = W[0]; kp.eWhh0l = W[1];
  kp.eWih1h = W[2]; kp.eWih1l = W[3];
  kp.eWhh1h = W[4]; kp.eWhh1l = W[5];
  kp.dWhh0h = W[6]; kp.dWhh0l = W[7];
  kp.dWih1h = W[8]; kp.dWih1l = W[9];
  kp.dWhh1h = W[10]; kp.dWhh1l = W[11];
  kp.h0h0 = sb + 0*(size_t)BH; kp.h0h1 = sb + 1*(size_t)BH;
  kp.h0l0 = sb + 2*(size_t)BH; kp.h0l1 = sb + 3*(size_t)BH;
  kp.h1h0 = sb + 4*(size_t)BH; kp.h1h1 = sb + 5*(size_t)BH;
  kp.h1l0 = sb + 6*(size_t)BH; kp.h1l1 = sb + 7*(size_t)BH;
  kp.c0 = c0; kp.c1 = c1; kp.pred = pred; kp.out = out; kp.bar = bar;

  (void)hipFuncSetAttribute((const void*)lstm_persist,
                            hipFuncAttributeMaxDynamicSharedMemorySize, LDSB);
  void* kargs[] = { (void*)&kp };
  hipError_t rc = hipLaunchCooperativeKernel((const void*)lstm_persist, dim3(256), dim3(256),
                                             kargs, LDSB, stream);
  if (rc != hipSuccess) {
    // fallback: plain launch — 256 blocks at 1 block/CU are co-resident on 256 CUs
    lstm_persist<<<dim3(256), dim3(256), LDSB, stream>>>(kp);
  }
  (void)in_sizes; (void)n_in; (void)out_size; (void)ws_size;
}